// Round 1
// baseline (30.488 us; speedup 1.0000x reference)
//
#include <hip/hip_runtime.h>
#include <math.h>

#define NQ 10
#define DIM 1024
#define NL 4
#define PI_F 3.14159265358979323846f

__device__ __forceinline__ float2 cmul(float2 a, float2 b) {
    return make_float2(a.x * b.x - a.y * b.y, a.x * b.y + a.y * b.x);
}

// Precompute the 40 fused layer matrices: M = RX(a0/2) * RZ(a2) * RY(a1) * RZ(a0)
// with a_k = tanh(theta)*pi. Batch-independent.
__global__ void prep_layer_mats(const float* __restrict__ theta, float* __restrict__ lm) {
    int idx = threadIdx.x;
    if (idx >= NL * NQ) return;
    float a0 = tanhf(theta[idx * 3 + 0]) * PI_F;
    float a1 = tanhf(theta[idx * 3 + 1]) * PI_F;
    float a2 = tanhf(theta[idx * 3 + 2]) * PI_F;

    // M = RZ(a0) = diag(e^{-i a0/2}, e^{i a0/2})
    float sz0, cz0; sincosf(a0 * 0.5f, &sz0, &cz0);
    float2 m00 = make_float2(cz0, -sz0);
    float2 m11 = make_float2(cz0,  sz0);
    // RY(a1) on the left (m01 = m10 = 0 before this)
    float sy, cy; sincosf(a1 * 0.5f, &sy, &cy);
    float2 t00 = make_float2(cy * m00.x, cy * m00.y);
    float2 t01 = make_float2(-sy * m11.x, -sy * m11.y);
    float2 t10 = make_float2(sy * m00.x, sy * m00.y);
    float2 t11 = make_float2(cy * m11.x, cy * m11.y);
    // RZ(a2) on the left: row0 *= e^{-i a2/2}, row1 *= e^{+i a2/2}
    float sz2, cz2; sincosf(a2 * 0.5f, &sz2, &cz2);
    float2 e0 = make_float2(cz2, -sz2), e1 = make_float2(cz2, sz2);
    t00 = cmul(e0, t00); t01 = cmul(e0, t01);
    t10 = cmul(e1, t10); t11 = cmul(e1, t11);
    // RX(a0*0.5) on the left: RX(th) = [[c, -i s], [-i s, c]], half-angle = a0*0.25
    float sx, cx; sincosf(a0 * 0.25f, &sx, &cx);
    float2 r00 = make_float2(cx * t00.x + sx * t10.y, cx * t00.y - sx * t10.x);
    float2 r01 = make_float2(cx * t01.x + sx * t11.y, cx * t01.y - sx * t11.x);
    float2 r10 = make_float2(cx * t10.x + sx * t00.y, cx * t10.y - sx * t00.x);
    float2 r11 = make_float2(cx * t11.x + sx * t01.y, cx * t11.y - sx * t01.x);
    float* o = lm + idx * 8;
    o[0] = r00.x; o[1] = r00.y; o[2] = r01.x; o[3] = r01.y;
    o[4] = r10.x; o[5] = r10.y; o[6] = r11.x; o[7] = r11.y;
}

// Apply a 2x2 complex matrix to qubit with bit position `bit`. 512 threads, each owns one pair.
__device__ __forceinline__ void apply1q(float2* st, const float2* U, int bit, int t) {
    int i0 = ((t >> bit) << (bit + 1)) | (t & ((1 << bit) - 1));
    int i1 = i0 | (1 << bit);
    float2 u00 = U[0], u01 = U[1], u10 = U[2], u11 = U[3];
    float2 a0 = st[i0], a1 = st[i1];
    float2 n0, n1;
    n0.x = u00.x * a0.x - u00.y * a0.y + u01.x * a1.x - u01.y * a1.y;
    n0.y = u00.x * a0.y + u00.y * a0.x + u01.x * a1.y + u01.y * a1.x;
    n1.x = u10.x * a0.x - u10.y * a0.y + u11.x * a1.x - u11.y * a1.y;
    n1.y = u10.x * a0.y + u10.y * a0.x + u11.x * a1.y + u11.y * a1.x;
    st[i0] = n0;
    st[i1] = n1;
    __syncthreads();
}

// Fused pass of all disjoint CZCNOT gates described by cmask (bits of control qubits;
// target bit is always control bit - 1). new[i] = sign * old[i ^ ((i&cmask)>>1)].
__device__ __forceinline__ void perm_pass(float2* st, int t, int cmask) {
    int i1 = t + 512;
    int f0 = (t & cmask) >> 1;
    int f1 = (i1 & cmask) >> 1;
    int j0 = t ^ f0, j1 = i1 ^ f1;
    int z0 = __popc(f0) - __popc(t & f0);
    int z1 = __popc(f1) - __popc(i1 & f1);
    float s0 = (z0 & 1) ? -1.f : 1.f;
    float s1 = (z1 & 1) ? -1.f : 1.f;
    float2 v0 = st[j0], v1 = st[j1];
    __syncthreads();
    st[t]  = make_float2(s0 * v0.x, s0 * v0.y);
    st[i1] = make_float2(s1 * v1.x, s1 * v1.y);
    __syncthreads();
}

__global__ __launch_bounds__(512) void qsim_kernel(const float* __restrict__ inputs,
                                                   const float* __restrict__ lm,
                                                   float* __restrict__ out) {
    const int b = blockIdx.x;
    const int t = threadIdx.x;
    __shared__ float2 st[DIM];
    __shared__ float2 mats[(NQ + NL * NQ) * 4];  // [0..39]: encoding mats, [40..199]: layer mats
    __shared__ float red[8][NQ];

    // Load precomputed layer matrices (160 float2)
    if (t < NL * NQ * 4) mats[NQ * 4 + t] = reinterpret_cast<const float2*>(lm)[t];

    // Compute fused encoding matrix per qubit: prod over f in {1,2,4,8,16} of RX(f*x/2)*RZ(f*x)
    if (t < NQ) {
        float x = tanhf(inputs[b * NQ + t]);
        float2 m00 = make_float2(1.f, 0.f), m01 = make_float2(0.f, 0.f);
        float2 m10 = make_float2(0.f, 0.f), m11 = make_float2(1.f, 0.f);
        #pragma unroll
        for (int k = 0; k < 5; k++) {
            float f = (float)(1 << k);
            float phi = f * x;
            float sh, ch; sincosf(phi * 0.5f, &sh, &ch);
            float2 e0 = make_float2(ch, -sh), e1 = make_float2(ch, sh);
            m00 = cmul(e0, m00); m01 = cmul(e0, m01);
            m10 = cmul(e1, m10); m11 = cmul(e1, m11);
            float sx, cxx; sincosf(phi * 0.25f, &sx, &cxx);
            float2 n00 = make_float2(cxx * m00.x + sx * m10.y, cxx * m00.y - sx * m10.x);
            float2 n01 = make_float2(cxx * m01.x + sx * m11.y, cxx * m01.y - sx * m11.x);
            float2 n10 = make_float2(cxx * m10.x + sx * m00.y, cxx * m10.y - sx * m00.x);
            float2 n11 = make_float2(cxx * m11.x + sx * m01.y, cxx * m11.y - sx * m01.x);
            m00 = n00; m01 = n01; m10 = n10; m11 = n11;
        }
        mats[t * 4 + 0] = m00; mats[t * 4 + 1] = m01;
        mats[t * 4 + 2] = m10; mats[t * 4 + 3] = m11;
    }

    // Init |00...0>
    st[t]       = make_float2(t == 0 ? 1.f : 0.f, 0.f);
    st[t + 512] = make_float2(0.f, 0.f);
    __syncthreads();

    // Encoding gates (qubit q -> bit 9-q)
    #pragma unroll
    for (int q = 0; q < NQ; q++) {
        apply1q(st, &mats[q * 4], 9 - q, t);
    }

    // Layers
    #pragma unroll
    for (int l = 0; l < NL; l++) {
        #pragma unroll
        for (int q = 0; q < NQ; q++) {
            apply1q(st, &mats[(NQ + l * NQ + q) * 4], 9 - q, t);
        }
        // even pairs (0,1),(2,3),(4,5),(6,7),(8,9): control bits {9,7,5,3,1}
        perm_pass(st, t, 0x2AA);
        // odd pairs (1,2),(3,4),(5,6),(7,8): control bits {8,6,4,2}
        perm_pass(st, t, 0x154);
    }

    // Expectations <Z_q> = sum_i |st[i]|^2 * (bit_q(i)==0 ? +1 : -1)
    float2 a = st[t], c = st[t + 512];
    float p0 = a.x * a.x + a.y * a.y;
    float p1 = c.x * c.x + c.y * c.y;
    float ex[NQ];
    #pragma unroll
    for (int q = 0; q < NQ; q++) {
        int bit = 9 - q;
        float s0 = ((t >> bit) & 1) ? -p0 : p0;
        float s1 = (((t + 512) >> bit) & 1) ? -p1 : p1;
        ex[q] = s0 + s1;
    }
    // wave-level reduce (64 lanes)
    #pragma unroll
    for (int q = 0; q < NQ; q++) {
        float v = ex[q];
        #pragma unroll
        for (int off = 32; off > 0; off >>= 1) v += __shfl_down(v, off, 64);
        ex[q] = v;
    }
    int wave = t >> 6, lane = t & 63;
    if (lane == 0) {
        #pragma unroll
        for (int q = 0; q < NQ; q++) red[wave][q] = ex[q];
    }
    __syncthreads();
    if (t < NQ) {
        float s = 0.f;
        #pragma unroll
        for (int w = 0; w < 8; w++) s += red[w][t];
        out[b * NQ + t] = s;
    }
}

extern "C" void kernel_launch(void* const* d_in, const int* in_sizes, int n_in,
                              void* d_out, int out_size, void* d_ws, size_t ws_size,
                              hipStream_t stream) {
    const float* inputs = (const float*)d_in[0];  // (512, 10) f32
    const float* theta  = (const float*)d_in[1];  // (4, 10, 3) f32
    float* out = (float*)d_out;                    // (512, 10) f32
    float* lm = (float*)d_ws;                      // 40 * 8 floats

    prep_layer_mats<<<1, 64, 0, stream>>>(theta, lm);
    qsim_kernel<<<512, 512, 0, stream>>>(inputs, lm, out);
}

// Round 2
// 26.343 us; speedup vs baseline: 1.1573x; 1.1573x over previous
//
#include <hip/hip_runtime.h>
#include <math.h>

#define PI_F 3.14159265358979323846f

__device__ __forceinline__ float2 cmul(float2 a, float2 b) {
    return make_float2(a.x * b.x - a.y * b.y, a.x * b.y + a.y * b.x);
}
__device__ __forceinline__ float2 cfma(float2 u, float2 v, float2 acc) {
    acc.x = fmaf(u.x, v.x, fmaf(-u.y, v.y, acc.x));
    acc.y = fmaf(u.x, v.y, fmaf(u.y, v.x, acc.y));
    return acc;
}

// ---------------- prep: 40 fused layer 2x2s + 4x4 w-axis matrices for layers 2-4 ----------------
// lm layout (floats): [0,320): 40 mats x 8 (u00,u01,u10,u11 as re,im)
//                     [320,416): 3 layers x 16 entries x 2 (M4 = CZCNOT*(L_l0 (x) L_l1))
__global__ void prep_layer_mats(const float* __restrict__ theta, float* __restrict__ lm) {
    __shared__ float sm[40][8];
    int idx = threadIdx.x;
    if (idx < 40) {
        float a0 = tanhf(theta[idx * 3 + 0]) * PI_F;
        float a1 = tanhf(theta[idx * 3 + 1]) * PI_F;
        float a2 = tanhf(theta[idx * 3 + 2]) * PI_F;
        float sz0, cz0; sincosf(a0 * 0.5f, &sz0, &cz0);
        float2 m00 = make_float2(cz0, -sz0);
        float2 m11 = make_float2(cz0,  sz0);
        float sy, cy; sincosf(a1 * 0.5f, &sy, &cy);
        float2 t00 = make_float2(cy * m00.x, cy * m00.y);
        float2 t01 = make_float2(-sy * m11.x, -sy * m11.y);
        float2 t10 = make_float2(sy * m00.x, sy * m00.y);
        float2 t11 = make_float2(cy * m11.x, cy * m11.y);
        float sz2, cz2; sincosf(a2 * 0.5f, &sz2, &cz2);
        float2 e0 = make_float2(cz2, -sz2), e1 = make_float2(cz2, sz2);
        t00 = cmul(e0, t00); t01 = cmul(e0, t01);
        t10 = cmul(e1, t10); t11 = cmul(e1, t11);
        float sx, cx; sincosf(a0 * 0.25f, &sx, &cx);
        float2 r00 = make_float2(cx * t00.x + sx * t10.y, cx * t00.y - sx * t10.x);
        float2 r01 = make_float2(cx * t01.x + sx * t11.y, cx * t01.y - sx * t11.x);
        float2 r10 = make_float2(cx * t10.x + sx * t00.y, cx * t10.y - sx * t00.x);
        float2 r11 = make_float2(cx * t11.x + sx * t01.y, cx * t11.y - sx * t01.x);
        float* o = lm + idx * 8;
        float* s = sm[idx];
        s[0]=o[0]=r00.x; s[1]=o[1]=r00.y; s[2]=o[2]=r01.x; s[3]=o[3]=r01.y;
        s[4]=o[4]=r10.x; s[5]=o[5]=r10.y; s[6]=o[6]=r11.x; s[7]=o[7]=r11.y;
    }
    __syncthreads();
    if (idx < 48) {
        int li = idx >> 4;            // 0..2 -> layers 2..4 (l = li+1)
        int e = idx & 15, row = e >> 2, col = e & 3;
        int lyr = li + 1;
        const float* U0 = sm[lyr * 10 + 0];
        const float* U1 = sm[lyr * 10 + 1];
        int sr = (row == 2) ? 3 : (row == 3) ? 2 : row;
        float sgn = (row == 2) ? -1.f : 1.f;
        int i0 = ((sr >> 1) * 2 + (col >> 1)) * 2;
        int i1 = ((sr & 1) * 2 + (col & 1)) * 2;
        float ax = U0[i0], ay = U0[i0 + 1], bx = U1[i1], by = U1[i1 + 1];
        lm[320 + (li * 16 + e) * 2]     = sgn * (ax * bx - ay * by);
        lm[320 + (li * 16 + e) * 2 + 1] = sgn * (ax * by + ay * bx);
    }
}

// ---------------- gate helpers (state: 4 amps in registers) ----------------
// amp index = (w<<8) | (l<<2) | r ; qubit q <-> bit 9-q

// 1q gate on local bit0 (qubit 9): pairs (a0,a1),(a2,a3)
__device__ __forceinline__ void gate_b0(float2 a[4], const float2* U) {
    float2 u00 = U[0], u01 = U[1], u10 = U[2], u11 = U[3];
    float2 n0 = cfma(u00, a[0], cmul(u01, a[1]));
    float2 n1 = cfma(u10, a[0], cmul(u11, a[1]));
    float2 n2 = cfma(u00, a[2], cmul(u01, a[3]));
    float2 n3 = cfma(u10, a[2], cmul(u11, a[3]));
    a[0] = n0; a[1] = n1; a[2] = n2; a[3] = n3;
}
// 1q gate on local bit1 (qubit 8): pairs (a0,a2),(a1,a3)
__device__ __forceinline__ void gate_b1(float2 a[4], const float2* U) {
    float2 u00 = U[0], u01 = U[1], u10 = U[2], u11 = U[3];
    float2 n0 = cfma(u00, a[0], cmul(u01, a[2]));
    float2 n2 = cfma(u10, a[0], cmul(u11, a[2]));
    float2 n1 = cfma(u00, a[1], cmul(u01, a[3]));
    float2 n3 = cfma(u10, a[1], cmul(u11, a[3]));
    a[0] = n0; a[1] = n1; a[2] = n2; a[3] = n3;
}
// 1q gate on lane bit p (amp bit p+2, qubit 7-p)
__device__ __forceinline__ void gate_lane(float2 a[4], const float2* U, int p, int l) {
    int mask = 1 << p;
    bool h = (l >> p) & 1;
    float2 al = h ? U[3] : U[0];   // coeff of own amp
    float2 be = h ? U[2] : U[1];   // coeff of partner amp
    #pragma unroll
    for (int r = 0; r < 4; r++) {
        float2 pa;
        pa.x = __shfl_xor(a[r].x, mask, 64);
        pa.y = __shfl_xor(a[r].y, mask, 64);
        a[r] = cfma(al, a[r], cmul(be, pa));
    }
}
// CZCNOT with ctrl lane bit C, tgt lane bit G: for ctrl=1 lanes, a <- sign * partner(a)
__device__ __forceinline__ void cz_lane(float2 a[4], int C, int G, int l) {
    int mask = 1 << G;
    bool act = (l >> C) & 1;
    float sgn = ((l >> G) & 1) ? 1.f : -1.f;
    #pragma unroll
    for (int r = 0; r < 4; r++) {
        float px = __shfl_xor(a[r].x, mask, 64);
        float py = __shfl_xor(a[r].y, mask, 64);
        a[r].x = act ? sgn * px : a[r].x;
        a[r].y = act ? sgn * py : a[r].y;
    }
}
// odd CZCNOT(1,2): ctrl = w bit0 (amp bit8), tgt = lane bit5
__device__ __forceinline__ void cz_odd12(float2 a[4], int w, int l) {
    bool act = w & 1;
    float sgn = (l & 32) ? 1.f : -1.f;
    #pragma unroll
    for (int r = 0; r < 4; r++) {
        float px = __shfl_xor(a[r].x, 32, 64);
        float py = __shfl_xor(a[r].y, 32, 64);
        a[r].x = act ? sgn * px : a[r].x;
        a[r].y = act ? sgn * py : a[r].y;
    }
}
// even CZCNOT(8,9): ctrl r bit1, tgt r bit0: a2 <- -a3, a3 <- a2 (all lanes)
__device__ __forceinline__ void cz_local89(float2 a[4]) {
    float2 t = a[2];
    a[2] = make_float2(-a[3].x, -a[3].y);
    a[3] = t;
}
// odd CZCNOT(7,8): ctrl amp bit2 = lane bit0, tgt amp bit1 = r bit1
__device__ __forceinline__ void cz_local78(float2 a[4], int l) {
    bool act = l & 1;
    float2 o0 = a[0], o1 = a[1];
    a[0] = act ? make_float2(-a[2].x, -a[2].y) : a[0];
    a[1] = act ? make_float2(-a[3].x, -a[3].y) : a[1];
    a[2] = act ? o0 : a[2];
    a[3] = act ? o1 : a[3];
}

__global__ __launch_bounds__(256) void qsim_kernel(const float* __restrict__ inputs,
                                                   const float* __restrict__ lm,
                                                   float* __restrict__ out) {
    const int b = blockIdx.x;
    const int T = threadIdx.x;
    const int l = T & 63;
    const int w = T >> 6;

    __shared__ float2 fm[10][4];          // fused enc+layer1 2x2 per qubit
    __shared__ float2 Lm[3][8][4];        // layers 2-4, qubits 2..9
    __shared__ float2 m4s[4][16];         // per-layer 4x4 on w-axis (q0,q1 gates + even CZ(0,1))
    __shared__ __align__(16) float2 xch[2][1024];
    __shared__ float red[4][10];

    if (T < 96) {
        int li = T >> 5, rest = T & 31, q = 2 + (rest >> 2), k = rest & 3;
        const float* s = lm + ((li + 1) * 10 + q) * 8 + k * 2;
        Lm[li][q - 2][k] = make_float2(s[0], s[1]);
    } else if (T < 144) {
        int j = T - 96, li = j >> 4, e = j & 15;
        const float* s = lm + 320 + (li * 16 + e) * 2;
        m4s[li + 1][e] = make_float2(s[0], s[1]);
    } else if (T >= 160 && T < 170) {
        int q = T - 160;
        float x = tanhf(inputs[b * 10 + q]);
        float2 m00 = make_float2(1.f, 0.f), m01 = make_float2(0.f, 0.f);
        float2 m10 = make_float2(0.f, 0.f), m11 = make_float2(1.f, 0.f);
        #pragma unroll
        for (int k = 0; k < 5; k++) {
            float f = (float)(1 << k);
            float phi = f * x;
            float sh, ch; sincosf(phi * 0.5f, &sh, &ch);
            float2 e0 = make_float2(ch, -sh), e1 = make_float2(ch, sh);
            m00 = cmul(e0, m00); m01 = cmul(e0, m01);
            m10 = cmul(e1, m10); m11 = cmul(e1, m11);
            float sx, cxx; sincosf(phi * 0.25f, &sx, &cxx);
            float2 n00 = make_float2(cxx * m00.x + sx * m10.y, cxx * m00.y - sx * m10.x);
            float2 n01 = make_float2(cxx * m01.x + sx * m11.y, cxx * m01.y - sx * m11.x);
            float2 n10 = make_float2(cxx * m10.x + sx * m00.y, cxx * m10.y - sx * m00.x);
            float2 n11 = make_float2(cxx * m11.x + sx * m01.y, cxx * m11.y - sx * m01.x);
            m00 = n00; m01 = n01; m10 = n10; m11 = n11;
        }
        // F = L1 * E
        const float* L1 = lm + q * 8;
        float2 l00 = make_float2(L1[0], L1[1]), l01 = make_float2(L1[2], L1[3]);
        float2 l10 = make_float2(L1[4], L1[5]), l11 = make_float2(L1[6], L1[7]);
        fm[q][0] = cfma(l00, m00, cmul(l01, m10));
        fm[q][1] = cfma(l00, m01, cmul(l01, m11));
        fm[q][2] = cfma(l10, m00, cmul(l11, m10));
        fm[q][3] = cfma(l10, m01, cmul(l11, m11));
    }
    __syncthreads();
    if (T < 16) {   // M4 for layer 1 from batch-dependent fm[0], fm[1]
        int row = T >> 2, col = T & 3;
        int sr = (row == 2) ? 3 : (row == 3) ? 2 : row;
        float sgn = (row == 2) ? -1.f : 1.f;
        float2 u0 = fm[0][(sr >> 1) * 2 + (col >> 1)];
        float2 u1 = fm[1][(sr & 1) * 2 + (col & 1)];
        float2 e = cmul(u0, u1);
        m4s[0][T] = make_float2(sgn * e.x, sgn * e.y);
    }
    __syncthreads();

    // init |0...0>
    float2 a[4];
    a[0] = make_float2(T == 0 ? 1.f : 0.f, 0.f);
    a[1] = make_float2(0.f, 0.f);
    a[2] = make_float2(0.f, 0.f);
    a[3] = make_float2(0.f, 0.f);

    #pragma unroll
    for (int L = 0; L < 4; L++) {
        const float2 (*G)[4] = (L == 0) ? (const float2(*)[4])&fm[2] : Lm[L - 1];
        // 1q gates q=2..7 (lane bits 5..0), q=8,9 (local)
        gate_lane(a, G[0], 5, l);
        gate_lane(a, G[1], 4, l);
        gate_lane(a, G[2], 3, l);
        gate_lane(a, G[3], 2, l);
        gate_lane(a, G[4], 1, l);
        gate_lane(a, G[5], 0, l);
        gate_b1(a, G[6]);
        gate_b0(a, G[7]);
        // w-axis 4x4: q0,q1 gates + even CZ(0,1)
        {
            int buf = L & 1;
            float4* wp = (float4*)&xch[buf][T << 2];
            wp[0] = make_float4(a[0].x, a[0].y, a[1].x, a[1].y);
            wp[1] = make_float4(a[2].x, a[2].y, a[3].x, a[3].y);
            __syncthreads();
            const float2* M4row = &m4s[L][w * 4];
            float2 mw = M4row[w];
            float2 n[4];
            #pragma unroll
            for (int r = 0; r < 4; r++) n[r] = cmul(mw, a[r]);
            #pragma unroll
            for (int j = 0; j < 3; j++) {
                int wo = (w + 1 + j) & 3;
                float2 c = M4row[wo];
                const float4* rp = (const float4*)&xch[buf][(wo << 8) | (l << 2)];
                float4 v0 = rp[0], v1 = rp[1];
                n[0] = cfma(c, make_float2(v0.x, v0.y), n[0]);
                n[1] = cfma(c, make_float2(v0.z, v0.w), n[1]);
                n[2] = cfma(c, make_float2(v1.x, v1.y), n[2]);
                n[3] = cfma(c, make_float2(v1.z, v1.w), n[3]);
            }
            a[0] = n[0]; a[1] = n[1]; a[2] = n[2]; a[3] = n[3];
        }
        // remaining even CZs: (2,3)->lane(5,4), (4,5)->lane(3,2), (6,7)->lane(1,0), (8,9)->local
        cz_lane(a, 5, 4, l);
        cz_lane(a, 3, 2, l);
        cz_lane(a, 1, 0, l);
        cz_local89(a);
        // odd CZs: (1,2), (3,4)->lane(4,3), (5,6)->lane(2,1), (7,8)->local-ish
        cz_odd12(a, w, l);
        cz_lane(a, 4, 3, l);
        cz_lane(a, 2, 1, l);
        cz_local78(a, l);
    }

    // expectations
    float p0 = a[0].x * a[0].x + a[0].y * a[0].y;
    float p1 = a[1].x * a[1].x + a[1].y * a[1].y;
    float p2 = a[2].x * a[2].x + a[2].y * a[2].y;
    float p3 = a[3].x * a[3].x + a[3].y * a[3].y;
    float S = p0 + p1 + p2 + p3;
    float e[10];
    e[9] = p0 - p1 + p2 - p3;
    e[8] = p0 + p1 - p2 - p3;
    #pragma unroll
    for (int q = 2; q <= 7; q++) {
        e[q] = ((l >> (7 - q)) & 1) ? -S : S;
    }
    e[1] = (w & 1) ? -S : S;
    e[0] = (w & 2) ? -S : S;
    #pragma unroll
    for (int q = 0; q < 10; q++) {
        float v = e[q];
        #pragma unroll
        for (int off = 32; off > 0; off >>= 1) v += __shfl_down(v, off, 64);
        e[q] = v;
    }
    if (l == 0) {
        #pragma unroll
        for (int q = 0; q < 10; q++) red[w][q] = e[q];
    }
    __syncthreads();
    if (T < 10) {
        out[b * 10 + T] = red[0][T] + red[1][T] + red[2][T] + red[3][T];
    }
}

extern "C" void kernel_launch(void* const* d_in, const int* in_sizes, int n_in,
                              void* d_out, int out_size, void* d_ws, size_t ws_size,
                              hipStream_t stream) {
    const float* inputs = (const float*)d_in[0];  // (512, 10) f32
    const float* theta  = (const float*)d_in[1];  // (4, 10, 3) f32
    float* out = (float*)d_out;                    // (512, 10) f32
    float* lm = (float*)d_ws;                      // 416 floats

    prep_layer_mats<<<1, 64, 0, stream>>>(theta, lm);
    qsim_kernel<<<512, 256, 0, stream>>>(inputs, lm, out);
}

// Round 3
// 16.189 us; speedup vs baseline: 1.8833x; 1.6273x over previous
//
#include <hip/hip_runtime.h>
#include <math.h>

#define PI_F 3.14159265358979323846f

__device__ __forceinline__ float2 cmul(float2 a, float2 b) {
    return make_float2(a.x * b.x - a.y * b.y, a.x * b.y + a.y * b.x);
}
__device__ __forceinline__ float2 cfma(float2 u, float2 v, float2 acc) {
    acc.x = fmaf(u.x, v.x, fmaf(-u.y, v.y, acc.x));
    acc.y = fmaf(u.x, v.y, fmaf(u.y, v.x, acc.y));
    return acc;
}

// 1q gate on local bit0 (qubit 9)
__device__ __forceinline__ void gate_b0(float2 a[4], const float2* U) {
    float2 u00 = U[0], u01 = U[1], u10 = U[2], u11 = U[3];
    float2 n0 = cfma(u00, a[0], cmul(u01, a[1]));
    float2 n1 = cfma(u10, a[0], cmul(u11, a[1]));
    float2 n2 = cfma(u00, a[2], cmul(u01, a[3]));
    float2 n3 = cfma(u10, a[2], cmul(u11, a[3]));
    a[0] = n0; a[1] = n1; a[2] = n2; a[3] = n3;
}
// 1q gate on local bit1 (qubit 8)
__device__ __forceinline__ void gate_b1(float2 a[4], const float2* U) {
    float2 u00 = U[0], u01 = U[1], u10 = U[2], u11 = U[3];
    float2 n0 = cfma(u00, a[0], cmul(u01, a[2]));
    float2 n2 = cfma(u10, a[0], cmul(u11, a[2]));
    float2 n1 = cfma(u00, a[1], cmul(u01, a[3]));
    float2 n3 = cfma(u10, a[1], cmul(u11, a[3]));
    a[0] = n0; a[1] = n1; a[2] = n2; a[3] = n3;
}
// 1q gate on lane bit p (qubit 7-p)
__device__ __forceinline__ void gate_lane(float2 a[4], const float2* U, int p, int l) {
    int mask = 1 << p;
    bool h = (l >> p) & 1;
    float2 al = h ? U[3] : U[0];
    float2 be = h ? U[2] : U[1];
    #pragma unroll
    for (int r = 0; r < 4; r++) {
        float2 pa;
        pa.x = __shfl_xor(a[r].x, mask, 64);
        pa.y = __shfl_xor(a[r].y, mask, 64);
        a[r] = cfma(al, a[r], cmul(be, pa));
    }
}

__global__ __launch_bounds__(256) void qsim_fused(const float* __restrict__ inputs,
                                                  const float* __restrict__ theta,
                                                  float* __restrict__ out) {
    const int b = blockIdx.x;
    const int T = threadIdx.x;
    const int l = T & 63;
    const int w = T >> 6;

    __shared__ float2 sm[40][4];          // per-layer fused 2x2 (RX*RZ*RY*RZ), layer*10+q
    __shared__ float2 ve[10][2];          // encoding vector E|0> per qubit (batch-dep)
    __shared__ float2 vq[10][2];          // L0-matrix * ve  (batch-dep)
    __shared__ float2 m4s[4][16];         // w-axis 4x4 per layer (q0,q1 gates + CZ(0,1)), L=1..3
    __shared__ __align__(16) float2 xch[2][1024];
    __shared__ float red[4][10];

    // ---- stage A: 40 layer mats; 10 encoding vectors ----
    if (T < 40) {
        float a0 = tanhf(theta[T * 3 + 0]) * PI_F;
        float a1 = tanhf(theta[T * 3 + 1]) * PI_F;
        float a2 = tanhf(theta[T * 3 + 2]) * PI_F;
        float sz0, cz0; sincosf(a0 * 0.5f, &sz0, &cz0);
        float2 m00 = make_float2(cz0, -sz0);
        float2 m11 = make_float2(cz0,  sz0);
        float sy, cy; sincosf(a1 * 0.5f, &sy, &cy);
        float2 t00 = make_float2(cy * m00.x, cy * m00.y);
        float2 t01 = make_float2(-sy * m11.x, -sy * m11.y);
        float2 t10 = make_float2(sy * m00.x, sy * m00.y);
        float2 t11 = make_float2(cy * m11.x, cy * m11.y);
        float sz2, cz2; sincosf(a2 * 0.5f, &sz2, &cz2);
        float2 e0 = make_float2(cz2, -sz2), e1 = make_float2(cz2, sz2);
        t00 = cmul(e0, t00); t01 = cmul(e0, t01);
        t10 = cmul(e1, t10); t11 = cmul(e1, t11);
        float sx, cx; sincosf(a0 * 0.25f, &sx, &cx);
        sm[T][0] = make_float2(cx * t00.x + sx * t10.y, cx * t00.y - sx * t10.x);
        sm[T][1] = make_float2(cx * t01.x + sx * t11.y, cx * t01.y - sx * t11.x);
        sm[T][2] = make_float2(cx * t10.x + sx * t00.y, cx * t10.y - sx * t00.x);
        sm[T][3] = make_float2(cx * t11.x + sx * t01.y, cx * t11.y - sx * t01.x);
    } else if (T >= 64 && T < 74) {
        int q = T - 64;
        float x = tanhf(inputs[b * 10 + q]);
        float2 v0 = make_float2(1.f, 0.f), v1 = make_float2(0.f, 0.f);
        #pragma unroll
        for (int k = 0; k < 5; k++) {
            float phi = (float)(1 << k) * x;
            float sh, ch; sincosf(phi * 0.5f, &sh, &ch);
            float2 n0 = cmul(make_float2(ch, -sh), v0);
            float2 n1 = cmul(make_float2(ch,  sh), v1);
            float sx, cxx; sincosf(phi * 0.25f, &sx, &cxx);
            v0 = make_float2(cxx * n0.x + sx * n1.y, cxx * n0.y - sx * n1.x);
            v1 = make_float2(cxx * n1.x + sx * n0.y, cxx * n1.y - sx * n0.x);
        }
        ve[q][0] = v0; ve[q][1] = v1;
    }
    __syncthreads();
    // ---- stage B: M4 for layers 1..3; vq = L0mat * ve ----
    if (T < 48) {
        int li = T >> 4, lyr = li + 1;
        int e = T & 15, row = e >> 2, col = e & 3;
        int sr = (row == 2) ? 3 : (row == 3) ? 2 : row;
        float sgn = (row == 2) ? -1.f : 1.f;
        float2 u0 = sm[lyr * 10 + 0][(sr >> 1) * 2 + (col >> 1)];
        float2 u1 = sm[lyr * 10 + 1][(sr & 1) * 2 + (col & 1)];
        float2 p = cmul(u0, u1);
        m4s[lyr][e] = make_float2(sgn * p.x, sgn * p.y);
    } else if (T >= 64 && T < 74) {
        int q = T - 64;
        float2 v0 = ve[q][0], v1 = ve[q][1];
        vq[q][0] = cfma(sm[q][0], v0, cmul(sm[q][1], v1));
        vq[q][1] = cfma(sm[q][2], v0, cmul(sm[q][3], v1));
    }
    __syncthreads();

    // ---- layer 0 complete (1q gates + even CZs + odd CZs) in closed form ----
    // state[i] = sign(i) * prod_q vq[q][bit_{9-q}(sigma(i))]
    // sigma(i) = pi_even(pi_odd(i)); masks: odd 0x154, even 0x2AA (full)
    const int i0 = (w << 8) | (l << 2);
    float2 a[4];
    {
        int ii = i0;
        int f1 = (ii & 0x154) >> 1; int m = ii ^ f1;
        int f2 = (m & 0x2AA) >> 1;  int sh = m ^ f2;
        float2 P = vq[7][(sh >> 2) & 1];
        P = cmul(P, vq[6][(sh >> 3) & 1]);
        P = cmul(P, vq[5][(sh >> 4) & 1]);
        P = cmul(P, vq[4][(sh >> 5) & 1]);
        P = cmul(P, vq[3][(sh >> 6) & 1]);
        P = cmul(P, vq[2][(sh >> 7) & 1]);
        P = cmul(P, vq[1][(sh >> 8) & 1]);
        P = cmul(P, vq[0][(sh >> 9) & 1]);
        #pragma unroll
        for (int r = 0; r < 4; r++) {
            int i = i0 | r;
            int g1 = (i & 0x154) >> 1; int mm = i ^ g1;
            int g2 = (mm & 0x2AA) >> 1; int s = mm ^ g2;
            int neg = (__popc(g1 & ~i) + __popc(g2 & ~mm)) & 1;
            float2 t = cmul(vq[8][(s >> 1) & 1], vq[9][s & 1]);
            t = cmul(P, t);
            a[r] = neg ? make_float2(-t.x, -t.y) : t;
        }
    }

    // ---- composite CZ constants for layers (CZ(0,1) excluded -> even mask 0xAA) ----
    int srcLane;
    float sg0, sg1, sg2, sg3;
    {
        #define CZP(r, SG) { int i = i0 | r; int g1 = (i & 0x154) >> 1; int mm = i ^ g1; \
                             int g2 = (mm & 0xAA) >> 1; int s = mm ^ g2; \
                             int neg = (__popc(g1 & ~i) + __popc(g2 & ~mm)) & 1; \
                             SG = neg ? -1.f : 1.f; if (r == 0) srcLane = (s >> 2) & 63; }
        CZP(0, sg0) CZP(1, sg1) CZP(2, sg2) CZP(3, sg3)
        #undef CZP
    }
    const bool L0 = l & 1;

    // ---- layers 1..3 ----
    #pragma unroll
    for (int L = 1; L < 4; L++) {
        const float2 (*G)[4] = (const float2(*)[4])&sm[L * 10 + 2];
        gate_lane(a, G[0], 5, l);
        gate_lane(a, G[1], 4, l);
        gate_lane(a, G[2], 3, l);
        gate_lane(a, G[3], 2, l);
        gate_lane(a, G[4], 1, l);
        gate_lane(a, G[5], 0, l);
        gate_b1(a, G[6]);
        gate_b0(a, G[7]);
        // w-axis 4x4 (q0,q1 1q gates + even CZ(0,1))
        {
            int buf = L & 1;
            float4* wp = (float4*)&xch[buf][T << 2];
            wp[0] = make_float4(a[0].x, a[0].y, a[1].x, a[1].y);
            wp[1] = make_float4(a[2].x, a[2].y, a[3].x, a[3].y);
            __syncthreads();
            const float2* M4row = &m4s[L][w * 4];
            float2 mw = M4row[w];
            float2 n[4];
            #pragma unroll
            for (int r = 0; r < 4; r++) n[r] = cmul(mw, a[r]);
            #pragma unroll
            for (int j = 0; j < 3; j++) {
                int wo = (w + 1 + j) & 3;
                float2 c = M4row[wo];
                const float4* rp = (const float4*)&xch[buf][(wo << 8) | (l << 2)];
                float4 v0 = rp[0], v1 = rp[1];
                n[0] = cfma(c, make_float2(v0.x, v0.y), n[0]);
                n[1] = cfma(c, make_float2(v0.z, v0.w), n[1]);
                n[2] = cfma(c, make_float2(v1.x, v1.y), n[2]);
                n[3] = cfma(c, make_float2(v1.z, v1.w), n[3]);
            }
            a[0] = n[0]; a[1] = n[1]; a[2] = n[2]; a[3] = n[3];
        }
        // composite of all remaining CZs (evens (2,3)(4,5)(6,7)(8,9), odds (1,2)(3,4)(5,6)(7,8))
        {
            float p0x = __shfl(a[0].x, srcLane, 64), p0y = __shfl(a[0].y, srcLane, 64);
            float p1x = __shfl(a[1].x, srcLane, 64), p1y = __shfl(a[1].y, srcLane, 64);
            float p2x = __shfl(a[2].x, srcLane, 64), p2y = __shfl(a[2].y, srcLane, 64);
            float p3x = __shfl(a[3].x, srcLane, 64), p3y = __shfl(a[3].y, srcLane, 64);
            // src_r: L0=0 -> {0,1,3,2}; L0=1 -> {3,2,0,1}
            a[0] = make_float2(sg0 * (L0 ? p3x : p0x), sg0 * (L0 ? p3y : p0y));
            a[1] = make_float2(sg1 * (L0 ? p2x : p1x), sg1 * (L0 ? p2y : p1y));
            a[2] = make_float2(sg2 * (L0 ? p0x : p3x), sg2 * (L0 ? p0y : p3y));
            a[3] = make_float2(sg3 * (L0 ? p1x : p2x), sg3 * (L0 ? p1y : p2y));
        }
    }

    // ---- expectations ----
    float p0 = a[0].x * a[0].x + a[0].y * a[0].y;
    float p1 = a[1].x * a[1].x + a[1].y * a[1].y;
    float p2 = a[2].x * a[2].x + a[2].y * a[2].y;
    float p3 = a[3].x * a[3].x + a[3].y * a[3].y;
    float S = p0 + p1 + p2 + p3;
    float e[10];
    e[9] = p0 - p1 + p2 - p3;
    e[8] = p0 + p1 - p2 - p3;
    #pragma unroll
    for (int q = 2; q <= 7; q++) e[q] = ((l >> (7 - q)) & 1) ? -S : S;
    e[1] = (w & 1) ? -S : S;
    e[0] = (w & 2) ? -S : S;
    #pragma unroll
    for (int q = 0; q < 10; q++) {
        float v = e[q];
        #pragma unroll
        for (int off = 32; off > 0; off >>= 1) v += __shfl_down(v, off, 64);
        e[q] = v;
    }
    if ((T & 63) == 0) {
        #pragma unroll
        for (int q = 0; q < 10; q++) red[w][q] = e[q];
    }
    __syncthreads();
    if (T < 10) {
        out[b * 10 + T] = red[0][T] + red[1][T] + red[2][T] + red[3][T];
    }
}

extern "C" void kernel_launch(void* const* d_in, const int* in_sizes, int n_in,
                              void* d_out, int out_size, void* d_ws, size_t ws_size,
                              hipStream_t stream) {
    const float* inputs = (const float*)d_in[0];  // (512, 10) f32
    const float* theta  = (const float*)d_in[1];  // (4, 10, 3) f32
    float* out = (float*)d_out;                    // (512, 10) f32
    qsim_fused<<<512, 256, 0, stream>>>(inputs, theta, out);
}

// Round 5
// 14.168 us; speedup vs baseline: 2.1519x; 1.1426x over previous
//
#include <hip/hip_runtime.h>
#include <math.h>

#define PI_F 3.14159265358979323846f

typedef unsigned u32v2 __attribute__((ext_vector_type(2)));

__device__ __forceinline__ float2 cmul(float2 a, float2 b) {
    return make_float2(a.x * b.x - a.y * b.y, a.x * b.y + a.y * b.x);
}
__device__ __forceinline__ float2 cfma(float2 u, float2 v, float2 acc) {
    acc.x = fmaf(u.x, v.x, fmaf(-u.y, v.y, acc.x));
    acc.y = fmaf(u.x, v.y, fmaf(u.y, v.x, acc.y));
    return acc;
}

// ---- lane-exchange primitives on different pipes ----
__device__ __forceinline__ float dpp_x1(float x) {  // partner = lane ^ 1 (quad_perm [1,0,3,2])
    return __int_as_float(__builtin_amdgcn_update_dpp(0, __float_as_int(x), 0xB1, 0xF, 0xF, true));
}
__device__ __forceinline__ float dpp_x2(float x) {  // partner = lane ^ 2 (quad_perm [2,3,0,1])
    return __int_as_float(__builtin_amdgcn_update_dpp(0, __float_as_int(x), 0x4E, 0xF, 0xF, true));
}
#if __has_builtin(__builtin_amdgcn_permlane32_swap)
__device__ __forceinline__ float pl32(float x, int l) {  // partner = lane ^ 32, VALU pipe
    // permlane32_swap(x,x): r.x = broadcast(lanes 0-31), r.y = broadcast(lanes 32-63)
    unsigned u = __float_as_uint(x);
    u32v2 r = __builtin_amdgcn_permlane32_swap(u, u, false, false);
    return __uint_as_float((l & 32) ? r.x : r.y);   // FIXED: was r.y : r.x (identity)
}
#else
__device__ __forceinline__ float pl32(float x, int l) { return __shfl_xor(x, 32, 64); }
#endif

// ---- gate application given partner fetch ----
__device__ __forceinline__ void gate_apply(float2 a[4], const float2 pa[4], float2 al, float2 be) {
    #pragma unroll
    for (int r = 0; r < 4; r++) a[r] = cfma(al, a[r], cmul(be, pa[r]));
}
__device__ __forceinline__ void gate_dpp1(float2 a[4], const float2* U, int l) {
    bool h = l & 1;
    float2 al = h ? U[3] : U[0], be = h ? U[2] : U[1];
    float2 pa[4];
    #pragma unroll
    for (int r = 0; r < 4; r++) { pa[r].x = dpp_x1(a[r].x); pa[r].y = dpp_x1(a[r].y); }
    gate_apply(a, pa, al, be);
}
__device__ __forceinline__ void gate_dpp2(float2 a[4], const float2* U, int l) {
    bool h = l & 2;
    float2 al = h ? U[3] : U[0], be = h ? U[2] : U[1];
    float2 pa[4];
    #pragma unroll
    for (int r = 0; r < 4; r++) { pa[r].x = dpp_x2(a[r].x); pa[r].y = dpp_x2(a[r].y); }
    gate_apply(a, pa, al, be);
}
__device__ __forceinline__ void gate_pl32(float2 a[4], const float2* U, int l) {
    bool h = l & 32;
    float2 al = h ? U[3] : U[0], be = h ? U[2] : U[1];
    float2 pa[4];
    #pragma unroll
    for (int r = 0; r < 4; r++) { pa[r].x = pl32(a[r].x, l); pa[r].y = pl32(a[r].y, l); }
    gate_apply(a, pa, al, be);
}
__device__ __forceinline__ void gate_shfl(float2 a[4], const float2* U, int p, int l) {
    int mask = 1 << p;
    bool h = (l >> p) & 1;
    float2 al = h ? U[3] : U[0], be = h ? U[2] : U[1];
    float2 pa[4];
    #pragma unroll
    for (int r = 0; r < 4; r++) {
        pa[r].x = __shfl_xor(a[r].x, mask, 64);
        pa[r].y = __shfl_xor(a[r].y, mask, 64);
    }
    gate_apply(a, pa, al, be);
}
// 1q gate on local bit0 (qubit 9)
__device__ __forceinline__ void gate_b0(float2 a[4], const float2* U) {
    float2 u00 = U[0], u01 = U[1], u10 = U[2], u11 = U[3];
    float2 n0 = cfma(u00, a[0], cmul(u01, a[1]));
    float2 n1 = cfma(u10, a[0], cmul(u11, a[1]));
    float2 n2 = cfma(u00, a[2], cmul(u01, a[3]));
    float2 n3 = cfma(u10, a[2], cmul(u11, a[3]));
    a[0] = n0; a[1] = n1; a[2] = n2; a[3] = n3;
}
// 1q gate on local bit1 (qubit 8)
__device__ __forceinline__ void gate_b1(float2 a[4], const float2* U) {
    float2 u00 = U[0], u01 = U[1], u10 = U[2], u11 = U[3];
    float2 n0 = cfma(u00, a[0], cmul(u01, a[2]));
    float2 n2 = cfma(u10, a[0], cmul(u11, a[2]));
    float2 n1 = cfma(u00, a[1], cmul(u01, a[3]));
    float2 n3 = cfma(u10, a[1], cmul(u11, a[3]));
    a[0] = n0; a[1] = n1; a[2] = n2; a[3] = n3;
}

__global__ __launch_bounds__(256) void qsim_fused(const float* __restrict__ inputs,
                                                  const float* __restrict__ theta,
                                                  float* __restrict__ out) {
    const int b = blockIdx.x;
    const int T = threadIdx.x;
    const int l = T & 63;
    const int w = T >> 6;

    __shared__ float2 sm[40][4];
    __shared__ float2 ve[10][2];
    __shared__ float2 vq[10][2];
    __shared__ float2 m4s[4][16];
    __shared__ __align__(16) float2 xch[2][1024];
    __shared__ float red[4][10];

    // ---- stage A: 40 layer mats; 10 encoding vectors (double-angle recurrence) ----
    if (T < 40) {
        float a0 = tanhf(theta[T * 3 + 0]) * PI_F;
        float a1 = tanhf(theta[T * 3 + 1]) * PI_F;
        float a2 = tanhf(theta[T * 3 + 2]) * PI_F;
        float sz0, cz0; sincosf(a0 * 0.5f, &sz0, &cz0);
        float2 m00 = make_float2(cz0, -sz0);
        float2 m11 = make_float2(cz0,  sz0);
        float sy, cy; sincosf(a1 * 0.5f, &sy, &cy);
        float2 t00 = make_float2(cy * m00.x, cy * m00.y);
        float2 t01 = make_float2(-sy * m11.x, -sy * m11.y);
        float2 t10 = make_float2(sy * m00.x, sy * m00.y);
        float2 t11 = make_float2(cy * m11.x, cy * m11.y);
        float sz2, cz2; sincosf(a2 * 0.5f, &sz2, &cz2);
        float2 e0 = make_float2(cz2, -sz2), e1 = make_float2(cz2, sz2);
        t00 = cmul(e0, t00); t01 = cmul(e0, t01);
        t10 = cmul(e1, t10); t11 = cmul(e1, t11);
        float sx, cx; sincosf(a0 * 0.25f, &sx, &cx);
        sm[T][0] = make_float2(cx * t00.x + sx * t10.y, cx * t00.y - sx * t10.x);
        sm[T][1] = make_float2(cx * t01.x + sx * t11.y, cx * t01.y - sx * t11.x);
        sm[T][2] = make_float2(cx * t10.x + sx * t00.y, cx * t10.y - sx * t00.x);
        sm[T][3] = make_float2(cx * t11.x + sx * t01.y, cx * t11.y - sx * t01.x);
    } else if (T >= 64 && T < 74) {
        int q = T - 64;
        float x = tanhf(inputs[b * 10 + q]);
        float sA[6], cA[6];
        sincosf(0.25f * x, &sA[0], &cA[0]);
        #pragma unroll
        for (int j = 1; j < 6; j++) {
            sA[j] = 2.f * sA[j - 1] * cA[j - 1];
            cA[j] = 1.f - 2.f * sA[j - 1] * sA[j - 1];
        }
        float2 v0 = make_float2(1.f, 0.f), v1 = make_float2(0.f, 0.f);
        #pragma unroll
        for (int k = 0; k < 5; k++) {
            float sh = sA[k + 1], ch = cA[k + 1];   // RZ half-angle = x*2^(k-1)
            float2 n0 = cmul(make_float2(ch, -sh), v0);
            float2 n1 = cmul(make_float2(ch,  sh), v1);
            float sx = sA[k], cx = cA[k];            // RX half-angle = x*2^(k-2)
            v0 = make_float2(cx * n0.x + sx * n1.y, cx * n0.y - sx * n1.x);
            v1 = make_float2(cx * n1.x + sx * n0.y, cx * n1.y - sx * n0.x);
        }
        ve[q][0] = v0; ve[q][1] = v1;
    }
    __syncthreads();
    // ---- stage B: M4 for layers 1..3; vq = L0mat * ve ----
    if (T < 48) {
        int li = T >> 4, lyr = li + 1;
        int e = T & 15, row = e >> 2, col = e & 3;
        int sr = (row == 2) ? 3 : (row == 3) ? 2 : row;
        float sgn = (row == 2) ? -1.f : 1.f;
        float2 u0 = sm[lyr * 10 + 0][(sr >> 1) * 2 + (col >> 1)];
        float2 u1 = sm[lyr * 10 + 1][(sr & 1) * 2 + (col & 1)];
        float2 p = cmul(u0, u1);
        m4s[lyr][e] = make_float2(sgn * p.x, sgn * p.y);
    } else if (T >= 64 && T < 74) {
        int q = T - 64;
        float2 v0 = ve[q][0], v1 = ve[q][1];
        vq[q][0] = cfma(sm[q][0], v0, cmul(sm[q][1], v1));
        vq[q][1] = cfma(sm[q][2], v0, cmul(sm[q][3], v1));
    }
    __syncthreads();

    // ---- layer 0 closed form ----
    const int i0 = (w << 8) | (l << 2);
    float2 a[4];
    {
        int f1 = (i0 & 0x154) >> 1; int m = i0 ^ f1;
        int f2 = (m & 0x2AA) >> 1;  int sh = m ^ f2;
        float2 t76 = cmul(vq[7][(sh >> 2) & 1], vq[6][(sh >> 3) & 1]);
        float2 t54 = cmul(vq[5][(sh >> 4) & 1], vq[4][(sh >> 5) & 1]);
        float2 t32 = cmul(vq[3][(sh >> 6) & 1], vq[2][(sh >> 7) & 1]);
        float2 t10 = cmul(vq[1][(sh >> 8) & 1], vq[0][(sh >> 9) & 1]);
        float2 P = cmul(cmul(t76, t54), cmul(t32, t10));
        #pragma unroll
        for (int r = 0; r < 4; r++) {
            int i = i0 | r;
            int g1 = (i & 0x154) >> 1; int mm = i ^ g1;
            int g2 = (mm & 0x2AA) >> 1; int s = mm ^ g2;
            int neg = (__popc(g1 & ~i) + __popc(g2 & ~mm)) & 1;
            float2 t = cmul(vq[8][(s >> 1) & 1], vq[9][s & 1]);
            t = cmul(P, t);
            a[r] = neg ? make_float2(-t.x, -t.y) : t;
        }
    }

    // ---- composite CZ constants (CZ(0,1) excluded -> even mask 0xAA) ----
    int srcLane;
    float sg0, sg1, sg2, sg3;
    {
        #define CZP(r, SG) { int i = i0 | r; int g1 = (i & 0x154) >> 1; int mm = i ^ g1; \
                             int g2 = (mm & 0xAA) >> 1; int s = mm ^ g2; \
                             int neg = (__popc(g1 & ~i) + __popc(g2 & ~mm)) & 1; \
                             SG = neg ? -1.f : 1.f; if (r == 0) srcLane = (s >> 2) & 63; }
        CZP(0, sg0) CZP(1, sg1) CZP(2, sg2) CZP(3, sg3)
        #undef CZP
    }
    const bool Lb = l & 1;

    // ---- layers 1..3 ----
    #pragma unroll
    for (int L = 1; L < 4; L++) {
        const float2 (*G)[4] = (const float2(*)[4])&sm[L * 10 + 2];
        gate_pl32(a, G[0], l);        // qubit 2, lane bit 5
        gate_shfl(a, G[1], 4, l);     // qubit 3
        gate_shfl(a, G[2], 3, l);     // qubit 4
        gate_shfl(a, G[3], 2, l);     // qubit 5
        gate_dpp2(a, G[4], l);        // qubit 6, lane bit 1
        gate_dpp1(a, G[5], l);        // qubit 7, lane bit 0
        gate_b1(a, G[6]);             // qubit 8
        gate_b0(a, G[7]);             // qubit 9
        // w-axis 4x4 (q0,q1 gates + even CZ(0,1))
        {
            int buf = L & 1;
            float4* wp = (float4*)&xch[buf][T << 2];
            wp[0] = make_float4(a[0].x, a[0].y, a[1].x, a[1].y);
            wp[1] = make_float4(a[2].x, a[2].y, a[3].x, a[3].y);
            __syncthreads();
            const float2* M4row = &m4s[L][w * 4];
            float2 mw = M4row[w];
            float2 n[4];
            #pragma unroll
            for (int r = 0; r < 4; r++) n[r] = cmul(mw, a[r]);
            #pragma unroll
            for (int j = 0; j < 3; j++) {
                int wo = (w + 1 + j) & 3;
                float2 c = M4row[wo];
                const float4* rp = (const float4*)&xch[buf][(wo << 8) | (l << 2)];
                float4 v0 = rp[0], v1 = rp[1];
                n[0] = cfma(c, make_float2(v0.x, v0.y), n[0]);
                n[1] = cfma(c, make_float2(v0.z, v0.w), n[1]);
                n[2] = cfma(c, make_float2(v1.x, v1.y), n[2]);
                n[3] = cfma(c, make_float2(v1.z, v1.w), n[3]);
            }
            a[0] = n[0]; a[1] = n[1]; a[2] = n[2]; a[3] = n[3];
        }
        // composite remaining CZs; last layer: signs irrelevant to |.|^2
        {
            float p0x = __shfl(a[0].x, srcLane, 64), p0y = __shfl(a[0].y, srcLane, 64);
            float p1x = __shfl(a[1].x, srcLane, 64), p1y = __shfl(a[1].y, srcLane, 64);
            float p2x = __shfl(a[2].x, srcLane, 64), p2y = __shfl(a[2].y, srcLane, 64);
            float p3x = __shfl(a[3].x, srcLane, 64), p3y = __shfl(a[3].y, srcLane, 64);
            if (L < 3) {
                a[0] = make_float2(sg0 * (Lb ? p3x : p0x), sg0 * (Lb ? p3y : p0y));
                a[1] = make_float2(sg1 * (Lb ? p2x : p1x), sg1 * (Lb ? p2y : p1y));
                a[2] = make_float2(sg2 * (Lb ? p0x : p3x), sg2 * (Lb ? p0y : p3y));
                a[3] = make_float2(sg3 * (Lb ? p1x : p2x), sg3 * (Lb ? p1y : p2y));
            } else {
                a[0] = make_float2(Lb ? p3x : p0x, Lb ? p3y : p0y);
                a[1] = make_float2(Lb ? p2x : p1x, Lb ? p2y : p1y);
                a[2] = make_float2(Lb ? p0x : p3x, Lb ? p0y : p3y);
                a[3] = make_float2(Lb ? p1x : p2x, Lb ? p1y : p2y);
            }
        }
    }

    // ---- expectations: one butterfly with per-bit signed captures ----
    float p0 = a[0].x * a[0].x + a[0].y * a[0].y;
    float p1 = a[1].x * a[1].x + a[1].y * a[1].y;
    float p2 = a[2].x * a[2].x + a[2].y * a[2].y;
    float p3 = a[3].x * a[3].x + a[3].y * a[3].y;
    float acc = p0 + p1 + p2 + p3;       // S
    float a8 = p0 + p1 - p2 - p3;        // qubit 8 (r bit1)
    float a9 = p0 - p1 + p2 - p3;        // qubit 9 (r bit0)
    float d0, d1, d2, d3, d4, d5;
    // stage 1 (DPP)
    { float pS = dpp_x1(acc); d0 = (l & 1) ? pS - acc : acc - pS; acc += pS;
      a8 += dpp_x1(a8); a9 += dpp_x1(a9); }
    // stage 2 (DPP)
    { float pS = dpp_x2(acc); d1 = (l & 2) ? pS - acc : acc - pS; acc += pS;
      a8 += dpp_x2(a8); a9 += dpp_x2(a9); d0 += dpp_x2(d0); }
    // stage 4 (DS)
    { float pS = __shfl_xor(acc, 4, 64); d2 = (l & 4) ? pS - acc : acc - pS; acc += pS;
      a8 += __shfl_xor(a8, 4, 64); a9 += __shfl_xor(a9, 4, 64);
      d0 += __shfl_xor(d0, 4, 64); d1 += __shfl_xor(d1, 4, 64); }
    // stage 8 (DS)
    { float pS = __shfl_xor(acc, 8, 64); d3 = (l & 8) ? pS - acc : acc - pS; acc += pS;
      a8 += __shfl_xor(a8, 8, 64); a9 += __shfl_xor(a9, 8, 64);
      d0 += __shfl_xor(d0, 8, 64); d1 += __shfl_xor(d1, 8, 64); d2 += __shfl_xor(d2, 8, 64); }
    // stage 16 (DS)
    { float pS = __shfl_xor(acc, 16, 64); d4 = (l & 16) ? pS - acc : acc - pS; acc += pS;
      a8 += __shfl_xor(a8, 16, 64); a9 += __shfl_xor(a9, 16, 64);
      d0 += __shfl_xor(d0, 16, 64); d1 += __shfl_xor(d1, 16, 64);
      d2 += __shfl_xor(d2, 16, 64); d3 += __shfl_xor(d3, 16, 64); }
    // stage 32 (permlane, VALU)
    { float pS = pl32(acc, l); d5 = (l & 32) ? pS - acc : acc - pS; acc += pS;
      a8 += pl32(a8, l); a9 += pl32(a9, l);
      d0 += pl32(d0, l); d1 += pl32(d1, l); d2 += pl32(d2, l);
      d3 += pl32(d3, l); d4 += pl32(d4, l); }

    if (l == 0) {
        red[w][0] = (w & 2) ? -acc : acc;   // qubit 0 (w bit1)
        red[w][1] = (w & 1) ? -acc : acc;   // qubit 1 (w bit0)
        red[w][2] = d5;  // qubit 2 <- lane bit 5
        red[w][3] = d4;
        red[w][4] = d3;
        red[w][5] = d2;
        red[w][6] = d1;
        red[w][7] = d0;  // qubit 7 <- lane bit 0
        red[w][8] = a8;
        red[w][9] = a9;
    }
    __syncthreads();
    if (T < 10) {
        out[b * 10 + T] = red[0][T] + red[1][T] + red[2][T] + red[3][T];
    }
}

extern "C" void kernel_launch(void* const* d_in, const int* in_sizes, int n_in,
                              void* d_out, int out_size, void* d_ws, size_t ws_size,
                              hipStream_t stream) {
    const float* inputs = (const float*)d_in[0];  // (512, 10) f32
    const float* theta  = (const float*)d_in[1];  // (4, 10, 3) f32
    float* out = (float*)d_out;                    // (512, 10) f32
    qsim_fused<<<512, 256, 0, stream>>>(inputs, theta, out);
}